// Round 3
// baseline (1099.092 us; speedup 1.0000x reference)
//
#include <hip/hip_runtime.h>
#include <hip/hip_bf16.h>

// DecoderRNN, fp32 in / fp32 out (reference dtypes), bf16 MFMA compute.
// Attention branch is dead code (softmax over a length-1 axis == 1 =>
// context == encoder_out; We/be/Wd/bd/Wf/bf never affect the output).
//   A) pre[t][g][b] = [emb(cap[b,t]), enc[b]] @ W_ih^T + b_ih + b_hh  (GEMM)
//      -> fp32, stored INSIDE d_out (dead space until out_kernel overwrites)
//   B) 64-step LSTM recurrence: 64 WGs, write-once-per-step Hall[t][b][h]
//      (bf16) + flag-array grid barrier (agent-scope atomics + fences)
//   C) out = Hall @ W_fc^T + b_fc   (2048 x 30000 x 512, fp32 accum/out)

#define BATCH 32
#define TT 64
#define VV 30000
#define HH 512
#define G4 2048     // 4*H
#define KX 768      // EMB + E
#define NWG 64

typedef __bf16 bf16x8 __attribute__((ext_vector_type(8)));
typedef float f32x4 __attribute__((ext_vector_type(4)));

#define MFMA(a, b, c) __builtin_amdgcn_mfma_f32_16x16x32_bf16((a), (b), (c), 0, 0, 0)

__device__ __forceinline__ float sigf(float x) {
    return 1.0f / (1.0f + __expf(-x));   // safe: x=+-inf -> 0/1
}
__device__ __forceinline__ float tanh_fast(float x) {
    return 1.0f - 2.0f / (__expf(2.0f * x) + 1.0f);   // safe at +-inf
}
__device__ __forceinline__ bf16x8 cvt8(const float* __restrict__ p) {
    const f32x4 a = *(const f32x4*)p;
    const f32x4 b = *(const f32x4*)(p + 4);
    bf16x8 r;
    r[0] = (__bf16)a[0]; r[1] = (__bf16)a[1]; r[2] = (__bf16)a[2]; r[3] = (__bf16)a[3];
    r[4] = (__bf16)b[0]; r[5] = (__bf16)b[1]; r[6] = (__bf16)b[2]; r[7] = (__bf16)b[3];
    return r;
}

// ---------------------------------------------------------------------------
// Kernel A: pre[t][g][b] fp32, layout [T][2048][32]. 128x128xK768 per WG.
// M index m = t*32 + b.
// ---------------------------------------------------------------------------
__global__ __launch_bounds__(256) void pre_kernel(
    const float* __restrict__ enc, const int* __restrict__ captions,
    const float* __restrict__ emb, const float* __restrict__ Wih,
    const float* __restrict__ bih, const float* __restrict__ bhh,
    float* __restrict__ pre) {
    __shared__ __bf16 aT[128 * 32];
    __shared__ __bf16 bT[128 * 32];
    __shared__ int capm[128];

    const int tid = threadIdx.x;
    const int nt = blockIdx.x;   // gate tile [0,16)
    const int mt = blockIdx.y;   // token tile [0,16)

    if (tid < 128) {
        int m = mt * 128 + tid;               // m = t*32 + b
        capm[tid] = captions[(m & 31) * TT + (m >> 5)];
    }

    const int lane = tid & 63, wv = tid >> 6;
    const int ln = lane & 15, quad = lane >> 4;
    const int wm = wv & 1, wn = wv >> 1;

    f32x4 acc[4][4] = {};
    __syncthreads();

    for (int kc = 0; kc < 24; ++kc) {
        const int k0 = kc * 32;
        for (int i = tid; i < 512; i += 256) {
            int r = i >> 2, seg = i & 3;
            const float* src;
            if (k0 < 512) {
                src = emb + (size_t)capm[r] * 512 + k0 + seg * 8;
            } else {
                int b = (mt * 128 + r) & 31;
                src = enc + b * 256 + (k0 - 512) + seg * 8;
            }
            *(bf16x8*)&aT[r * 32 + seg * 8] = cvt8(src);
            *(bf16x8*)&bT[r * 32 + seg * 8] =
                cvt8(&Wih[(size_t)(nt * 128 + r) * KX + k0 + seg * 8]);
        }
        __syncthreads();
        bf16x8 af[4], bfr[4];
        for (int x = 0; x < 4; ++x) {
            af[x]  = *(const bf16x8*)&aT[(wm * 64 + x * 16 + ln) * 32 + quad * 8];
            bfr[x] = *(const bf16x8*)&bT[(wn * 64 + x * 16 + ln) * 32 + quad * 8];
        }
        for (int mi = 0; mi < 4; ++mi)
            for (int ni = 0; ni < 4; ++ni)
                acc[mi][ni] = MFMA(af[mi], bfr[ni], acc[mi][ni]);
        __syncthreads();
    }

    for (int ni = 0; ni < 4; ++ni) {
        int g = nt * 128 + wn * 64 + ni * 16 + ln;
        float bias = bih[g] + bhh[g];
        for (int mi = 0; mi < 4; ++mi) {
            int m = mt * 128 + wm * 64 + mi * 16 + quad * 4;  // m = t*32+b, b%4==0
            int t = m >> 5, b = m & 31;
            f32x4 v = acc[mi][ni];
            v[0] += bias; v[1] += bias; v[2] += bias; v[3] += bias;
            *(f32x4*)&pre[((size_t)t * G4 + g) * BATCH + b] = v;
        }
    }
}

// ---------------------------------------------------------------------------
// Kernel B: recurrence. WG w owns h-cols [8w,8w+8) => 32 gate rows (LDS, bf16).
// Hall[t][b][h] (bf16) is write-once per step. Flag-array barrier: release
// fence + flags[t*64+w]=1; next step polls 64 flags, acquire fence.
// A-fragments (h_{t-1}) load directly from Hall (global) per MFMA step.
// ---------------------------------------------------------------------------
__global__ __launch_bounds__(256) void rnn_kernel(
    const float* __restrict__ pre, const float* __restrict__ Whh,
    __bf16* __restrict__ Hall, unsigned* __restrict__ flags) {
    __shared__ __bf16 whh[32 * 520];   // 32 gate rows x 512 (+8 pad)
    __shared__ float gst[32 * 36];     // gates [32 glocal][32 b] (+4 pad)

    const int tid = threadIdx.x;
    const int w = blockIdx.x;
    const int lane = tid & 63, wv = tid >> 6;
    const int ln = lane & 15, quad = lane >> 4;
    const int mi = wv & 1, ni = wv >> 1;       // wave -> 16x16 tile of [32b][32g]
    const int m_pw = tid & 31, nl = tid >> 5;  // pointwise (batch, local h col)

    for (int i = tid; i < 32 * 64; i += 256) {
        int r = i >> 6, k = (i & 63) << 3;
        int g = (r >> 3) * 512 + w * 8 + (r & 7);
        *(bf16x8*)&whh[r * 520 + k] = cvt8(&Whh[(size_t)g * HH + k]);
    }
    float c = 0.0f;
    __syncthreads();

    const int glocal = ni * 16 + ln;
    const int gate = (glocal >> 3) * 512 + w * 8 + (glocal & 7);
    const int b0 = mi * 16 + quad * 4;
    const size_t arow = (size_t)(mi * 16 + ln) * HH;   // A-frag row offset

    for (int t = 0; t < TT; ++t) {
        if (t > 0) {
            if (tid < 64) {
                while (__hip_atomic_load(&flags[(t - 1) * 64 + tid],
                                         __ATOMIC_RELAXED,
                                         __HIP_MEMORY_SCOPE_AGENT) == 0) {}
            }
            __builtin_amdgcn_fence(__ATOMIC_ACQUIRE, "agent");
        }
        __syncthreads();

        f32x4 acc = *(const f32x4*)&pre[((size_t)t * G4 + gate) * BATCH + b0];
        if (t > 0) {
            const __bf16* hrow = Hall + (size_t)(t - 1) * BATCH * HH + arow;
            for (int kc = 0; kc < 16; ++kc) {
                bf16x8 a = *(const bf16x8*)&hrow[kc * 32 + quad * 8];
                bf16x8 b = *(const bf16x8*)&whh[glocal * 520 + kc * 32 + quad * 8];
                acc = MFMA(a, b, acc);
            }
        }
        *(f32x4*)&gst[glocal * 36 + b0] = acc;
        __syncthreads();

        float gi = gst[(nl)      * 36 + m_pw];
        float gf = gst[(8 + nl)  * 36 + m_pw];
        float gg = gst[(16 + nl) * 36 + m_pw];
        float go = gst[(24 + nl) * 36 + m_pw];
        c = sigf(gf) * c + sigf(gi) * tanh_fast(gg);
        float h = sigf(go) * tanh_fast(c);
        Hall[((size_t)t * BATCH + m_pw) * HH + w * 8 + nl] = (__bf16)h;

        __syncthreads();   // drains all waves' Hall stores (vmcnt) before fence
        if (tid == 0) {
            __builtin_amdgcn_fence(__ATOMIC_RELEASE, "agent");
            __hip_atomic_store(&flags[t * 64 + w], 1u, __ATOMIC_RELAXED,
                               __HIP_MEMORY_SCOPE_AGENT);
        }
    }
}

// ---------------------------------------------------------------------------
// Kernel C: out[b][t][n] = Hall[t*32+b][:] . Wfc[n][:] + bfc[n]   (fp32 out)
// ---------------------------------------------------------------------------
__global__ __launch_bounds__(256) void out_kernel(
    const __bf16* __restrict__ Hall, const float* __restrict__ Wfc,
    const float* __restrict__ bfc, float* __restrict__ out) {
    __shared__ __bf16 aT[128 * 32];
    __shared__ __bf16 bT[128 * 32];

    const int tid = threadIdx.x;
    const int nt = blockIdx.x;   // [0,235)
    const int mt = blockIdx.y;   // [0,16)
    const int lane = tid & 63, wv = tid >> 6;
    const int ln = lane & 15, quad = lane >> 4;
    const int wm = wv & 1, wn = wv >> 1;

    f32x4 acc[4][4] = {};
    const size_t aBase = (size_t)mt * 128 * HH;

    for (int kc = 0; kc < 16; ++kc) {
        const int k0 = kc * 32;
        for (int i = tid; i < 512; i += 256) {
            int r = i >> 2, seg = i & 3;
            *(bf16x8*)&aT[r * 32 + seg * 8] =
                *(const bf16x8*)&Hall[aBase + (size_t)r * HH + k0 + seg * 8];
            int gr = nt * 128 + r;
            if (gr >= VV) gr = VV - 1;   // clamp (stores guarded)
            *(bf16x8*)&bT[r * 32 + seg * 8] =
                cvt8(&Wfc[(size_t)gr * HH + k0 + seg * 8]);
        }
        __syncthreads();
        bf16x8 af[4], bfr[4];
        for (int x = 0; x < 4; ++x) {
            af[x]  = *(const bf16x8*)&aT[(wm * 64 + x * 16 + ln) * 32 + quad * 8];
            bfr[x] = *(const bf16x8*)&bT[(wn * 64 + x * 16 + ln) * 32 + quad * 8];
        }
        for (int mi = 0; mi < 4; ++mi)
            for (int ni = 0; ni < 4; ++ni)
                acc[mi][ni] = MFMA(af[mi], bfr[ni], acc[mi][ni]);
        __syncthreads();
    }

    for (int ni = 0; ni < 4; ++ni) {
        int n = nt * 128 + wn * 64 + ni * 16 + ln;
        if (n >= VV) continue;
        float bias = bfc[n];
        for (int mi = 0; mi < 4; ++mi) {
            int m = mt * 128 + wm * 64 + mi * 16 + quad * 4;  // m = t*32+b
            for (int r = 0; r < 4; ++r) {
                int mm = m + r, t = mm >> 5, b = mm & 31;
                out[((size_t)b * TT + t) * VV + n] = acc[mi][ni][r] + bias;
            }
        }
    }
}

// ---------------------------------------------------------------------------
extern "C" void kernel_launch(void* const* d_in, const int* in_sizes, int n_in,
                              void* d_out, int out_size, void* d_ws, size_t ws_size,
                              hipStream_t stream) {
    const float* enc      = (const float*)d_in[0];
    const int*   captions = (const int*)d_in[1];
    // d_in[2..7]: We, be, Wd, bd, Wf, bf — dead (softmax over length-1 == 1)
    const float* emb      = (const float*)d_in[8];
    const float* Wih      = (const float*)d_in[9];
    const float* Whh      = (const float*)d_in[10];
    const float* bih      = (const float*)d_in[11];
    const float* bhh      = (const float*)d_in[12];
    const float* Wfc      = (const float*)d_in[13];
    const float* bfc      = (const float*)d_in[14];
    float* out = (float*)d_out;

    // pre (16.8 MB fp32) lives INSIDE d_out (245.8 MB fp32) — dead space until
    // out_kernel overwrites it, strictly after rnn_kernel consumed it.
    float* pre = (float*)d_out;

    uint8_t* w = (uint8_t*)d_ws;
    unsigned* flags = (unsigned*)w;                 // 64*64 u32 = 16 KiB
    __bf16*   Hall  = (__bf16*)(w + 16384);         // [T][B][H] bf16 = 2 MiB

    hipMemsetAsync(flags, 0, 16384, stream);        // ws is poisoned each launch

    pre_kernel<<<dim3(16, 16), 256, 0, stream>>>(enc, captions, emb, Wih, bih, bhh, pre);
    rnn_kernel<<<dim3(NWG), 256, 0, stream>>>(pre, Whh, Hall, flags);
    out_kernel<<<dim3(235, 16), 256, 0, stream>>>(Hall, Wfc, bfc, out);
}